// Round 10
// baseline (608.359 us; speedup 1.0000x reference)
//
#include <hip/hip_runtime.h>
#include <hip/hip_bf16.h>
#include <math.h>

// ---------------------------------------------------------------------------
// Seq2Seq: enc GRU (T=50) + tag GRU (T=20) -> proj -> dec GRU (T=40)
//          -> logits GEMM (1280x50003, K=256, bf16 MFMA) -> LSE -> NLL loss
//
// Round 10: producer-consumer overlap of dec scan and logits GEMM.
//  * k_declog fuses both: blocks 0,1 = dec scan (publishes progress via
//    vmcnt(0)+threadfence+agent-release every 2 steps); blocks 2+ = logits
//    (8 waves = 2 M-tiles sharing one B-tile), mpair-major dispatch so
//    needed timestep grows with dispatch order; spin+acquire before A reads.
//  * gi stored bf16 (halves traffic, error well under threshold).
//  * scan: 42 weight frags in regs (168 VGPR) + 6 (ks=7) in LDS -> fused
//    kernel LDS union = 66KB.
// ---------------------------------------------------------------------------

#define H 256
#define H3 768
#define NBATCH 32
#define TIN 50
#define TTGT 40
#define TTAG 20
#define VSZ 50003
#define VP 50048          // padded to 64
#define NT 782            // VP / 64
#define MT 1280           // TTGT * NBATCH
#define NGI 330           // 110 timesteps * 3 gates
#define NCVT 12512        // VP*H/4/256

typedef float f32x4 __attribute__((ext_vector_type(4)));
typedef short short8 __attribute__((ext_vector_type(8)));

__device__ __forceinline__ float dot4(float4 a, float4 b) {
    return a.x * b.x + a.y * b.y + a.z * b.z + a.w * b.w;
}

__device__ __forceinline__ float bf2f(short s) {
    unsigned int u = ((unsigned int)(unsigned short)s) << 16;
    return __builtin_bit_cast(float, u);
}

// barrier with LDS-only drain: leaves global loads in flight
__device__ __forceinline__ void bar_lgkm() {
    asm volatile("s_waitcnt lgkmcnt(0)" ::: "memory");
    __builtin_amdgcn_s_barrier();
    __builtin_amdgcn_sched_barrier(0);
}

// ---------------- prep: Wih/proj transpose + Whh -> MFMA-B fragments -------
// fragment order: f = ks*6 + hf*3 + q;  row = q*256 + w*32 + hf*16 + lr
__global__ void k_prep(const float* eWih, const float* tWih, const float* dWih,
                       const float* projW, const float* eWhh, const float* tWhh,
                       const float* dWhh, float* d0, float* d1, float* d2,
                       float* d3, __hip_bfloat16* p0, __hip_bfloat16* p1,
                       __hip_bfloat16* p2, int* prog) {
    int which = blockIdx.y;
    if (which == 0 && blockIdx.x == 0 && threadIdx.x < 2)
        prog[threadIdx.x] = 0;
    if (which < 4) {
        const float* s;
        float* d;
        int N, K;
        switch (which) {
            case 0: s = eWih; d = d0; N = H3; K = H; break;
            case 1: s = tWih; d = d1; N = H3; K = H; break;
            case 2: s = dWih; d = d2; N = H3; K = H; break;
            default: s = projW; d = d3; N = H; K = 2 * H; break;
        }
        int n = blockIdx.x;
        if (n >= N) return;
        for (int k = threadIdx.x; k < K; k += 256)
            d[(size_t)(k >> 2) * (N * 4) + n * 4 + (k & 3)] = s[(size_t)n * K + k];
    } else {
        if (blockIdx.x >= 96) return;
        const float* s = which == 4 ? eWhh : (which == 5 ? tWhh : dWhh);
        __hip_bfloat16* d = which == 4 ? p0 : (which == 5 ? p1 : p2);
        int idx = blockIdx.x * 256 + threadIdx.x;  // 0..24575
        int lane = idx & 63;
        int f = (idx >> 6) % 48;
        int w = idx / (48 * 64);
        int ks = f / 6, rem = f % 6;
        int hf = rem / 3, q = rem % 3;
        int row = (q << 8) + (w << 5) + (hf << 4) + (lane & 15);
        int k = (ks << 5) + ((lane >> 4) << 3);
#pragma unroll
        for (int j = 0; j < 8; ++j)
            d[(size_t)idx * 8 + j] = __float2bfloat16(s[(size_t)row * H + k + j]);
    }
}

// ---------------- gi -> per-lane MFMA layout (bf16)  [+ outW cvt] ----------
// GIP[t][loc][w][hf][reg][lane][4] bf16 = {r,z,n,pad}; bih(+bhh r,z) folded.
__global__ __launch_bounds__(256) void k_gi_cvt(
    const int* in_toks, const int* tag_toks, const int* tgt_toks,
    const float* enc_emb, const float* tag_emb, const float* W4e,
    const float* W4t, const float* W4d, const float* bih_e, const float* bhh_e,
    const float* bih_t, const float* bhh_t, const float* bih_d,
    const float* bhh_d, __hip_bfloat16* gi_e, __hip_bfloat16* gi_t,
    __hip_bfloat16* gi_d, const float* outW, __hip_bfloat16* outWb) {
    int bx = blockIdx.x, tid = threadIdx.x;
    if (bx >= NGI) {
        int i4 = ((bx - NGI) * 256 + tid) * 4;
        if (i4 >= VP * H) return;
        int row = i4 >> 8;
        float4 v;
        if (row < VSZ) v = *(const float4*)(outW + i4);
        else v = make_float4(0.f, 0.f, 0.f, 0.f);
        outWb[i4 + 0] = __float2bfloat16(v.x);
        outWb[i4 + 1] = __float2bfloat16(v.y);
        outWb[i4 + 2] = __float2bfloat16(v.z);
        outWb[i4 + 3] = __float2bfloat16(v.w);
        return;
    }
    __shared__ float x[NBATCH][H];
    int g = bx % 3, tt = bx / 3;
    const int* toks;
    const float* emb;
    const float* W4;
    const float* bihp;
    const float* bhhp;
    __hip_bfloat16* gip;
    int t, mode;
    if (tt < TIN) {
        toks = in_toks; emb = enc_emb; W4 = W4e; bihp = bih_e; bhhp = bhh_e;
        gip = gi_e; t = tt; mode = 0;
    } else if (tt < TIN + TTAG) {
        toks = tag_toks; emb = tag_emb; W4 = W4t; bihp = bih_t; bhhp = bhh_t;
        gip = gi_t; t = tt - TIN; mode = 0;
    } else {
        toks = tgt_toks; emb = enc_emb; W4 = W4d; bihp = bih_d; bhhp = bhh_d;
        gip = gi_d; t = tt - TIN - TTAG; mode = 2;
    }
    for (int b = 0; b < NBATCH; ++b) {
        int tok;
        if (mode == 2) tok = (t == 0) ? 1 : toks[(t - 1) * NBATCH + b];
        else tok = toks[t * NBATCH + b];
        float v = emb[(size_t)tok * H + tid];
        if (mode == 2) v = fmaxf(v, 0.0f);
        x[b][tid] = v;
    }
    __syncthreads();
    int nb_ = tid & 63, mg = tid >> 6;
    float acc[4][8];
#pragma unroll
    for (int j = 0; j < 4; ++j)
#pragma unroll
        for (int mi = 0; mi < 8; ++mi) acc[j][mi] = 0.f;
    for (int k4 = 0; k4 < 64; ++k4) {
        const float4* wrow = (const float4*)(W4 + (size_t)k4 * 3072);
        float4 w0 = wrow[g * 256 + nb_];
        float4 w1 = wrow[g * 256 + nb_ + 64];
        float4 w2 = wrow[g * 256 + nb_ + 128];
        float4 w3 = wrow[g * 256 + nb_ + 192];
#pragma unroll
        for (int mi = 0; mi < 8; ++mi) {
            float4 xv = *(const float4*)&x[mg * 8 + mi][k4 * 4];
            acc[0][mi] += dot4(xv, w0);
            acc[1][mi] += dot4(xv, w1);
            acc[2][mi] += dot4(xv, w2);
            acc[3][mi] += dot4(xv, w3);
        }
    }
#pragma unroll
    for (int j = 0; j < 4; ++j) {
        int n = g * 256 + nb_ + j * 64;
        float bv = bihp[n] + (g < 2 ? bhhp[n] : 0.0f);
        int nn = n & 255;
        int ww = nn >> 5, hf = (nn >> 4) & 1, lrr = nn & 15;
#pragma unroll
        for (int mi = 0; mi < 8; ++mi) {
            int bm = mg * 8 + mi;
            int locb = bm >> 4, lmm = bm & 15;
            int lgg = lmm >> 2, reg = lmm & 3;
            size_t idx = ((size_t)(t * 2 + locb) * 8 + ww) * 2048 +
                         hf * 1024 + reg * 256 + (lgg * 16 + lrr) * 4 + g;
            gip[idx] = __float2bfloat16(acc[j][mi] + bv);
        }
    }
}

// ---------------- enc+tag GRU scan (standalone, no output stream) ----------
__global__ __launch_bounds__(512) void k_scan(
    int nset1,
    const __hip_bfloat16* gi1, const __hip_bfloat16* W1, const float* bhh1,
    float* hT1, int T1,
    const __hip_bfloat16* gi2, const __hip_bfloat16* W2, const float* bhh2,
    float* hT2, int T2) {
    __shared__ uint4 WL[6 * 8 * 64];   // 49.2KB: frags ks=7
    __shared__ uint4 HBF[2][512];      // 16KB bf16 h dbuf

    int blk = blockIdx.x, tid = threadIdx.x;
    const __hip_bfloat16 *gip, *Wg;
    const float* bhh;
    float* hTp;
    int T, loc;
    if (blk < nset1) {
        gip = gi1; Wg = W1; bhh = bhh1; hTp = hT1; T = T1; loc = blk;
    } else {
        gip = gi2; Wg = W2; bhh = bhh2; hTp = hT2; T = T2; loc = blk - nset1;
    }
    int mb = loc * 16;
    int w = tid >> 6, lane = tid & 63, lr = lane & 15, lg = lane >> 4;

    short8 wreg[42];
    const uint4* Wg4 = (const uint4*)Wg;
#pragma unroll
    for (int f = 0; f < 42; ++f) {
        uint4 v = Wg4[(size_t)(w * 48 + f) * 64 + lane];
        wreg[f] = *(short8*)&v;
    }
#pragma unroll
    for (int i = 0; i < 6; ++i)
        WL[(w * 6 + i) * 64 + lane] = Wg4[(size_t)(w * 48 + 42 + i) * 64 + lane];

    float bnv[2];
    bnv[0] = bhh[512 + w * 32 + lr];
    bnv[1] = bhh[512 + w * 32 + 16 + lr];

    float hprev[8];
    short* HB16 = (short*)HBF;
#pragma unroll
    for (int hf = 0; hf < 2; ++hf)
#pragma unroll
        for (int reg = 0; reg < 4; ++reg) {
            int row = lg * 4 + reg;
            hprev[hf * 4 + reg] = 0.0f;
            int slot = (w * 4 + hf * 2 + (lr >> 3)) ^ (row & 7);
            HB16[row * 256 + slot * 8 + (lr & 7)] = 0;
        }
    uint2 gv[8];
    {
        const __hip_bfloat16* gp = gip + ((size_t)loc * 8 + w) * 2048;
#pragma unroll
        for (int i = 0; i < 8; ++i)
            gv[i] = *(const uint2*)(gp + (i >> 2) * 1024 + (i & 3) * 256 + lane * 4);
    }
    __syncthreads();

    const short8* HSbase = (const short8*)HBF;
    const short8* WLs = (const short8*)WL;
    for (int t = 0; t < T; ++t) {
        int p = t & 1, p2 = p ^ 1;
        const short8* HS = HSbase + p * 512;
        f32x4 acc[6];
        acc[0] = (f32x4){0.f, 0.f, 0.f, 0.f};
        acc[1] = acc[0];
        acc[2] = (f32x4){bnv[0], bnv[0], bnv[0], bnv[0]};
        acc[3] = acc[0];
        acc[4] = acc[0];
        acc[5] = (f32x4){bnv[1], bnv[1], bnv[1], bnv[1]};
#pragma unroll
        for (int ks = 0; ks < 7; ++ks) {
            short8 a = HS[lr * 32 + ((ks * 4 + lg) ^ (lr & 7))];
#pragma unroll
            for (int hf = 0; hf < 2; ++hf)
#pragma unroll
                for (int q = 0; q < 3; ++q)
                    acc[hf * 3 + q] = __builtin_amdgcn_mfma_f32_16x16x32_bf16(
                        a, wreg[ks * 6 + hf * 3 + q], acc[hf * 3 + q], 0, 0, 0);
        }
        {
            short8 a = HS[lr * 32 + ((28 + lg) ^ (lr & 7))];
#pragma unroll
            for (int hf = 0; hf < 2; ++hf)
#pragma unroll
                for (int q = 0; q < 3; ++q) {
                    short8 bv = WLs[(w * 6 + hf * 3 + q) * 64 + lane];
                    acc[hf * 3 + q] = __builtin_amdgcn_mfma_f32_16x16x32_bf16(
                        a, bv, acc[hf * 3 + q], 0, 0, 0);
                }
        }
#pragma unroll
        for (int hf = 0; hf < 2; ++hf)
#pragma unroll
            for (int reg = 0; reg < 4; ++reg) {
                uint2 u = gv[hf * 4 + reg];
                float gr = bf2f((short)(u.x & 0xffff));
                float gz = bf2f((short)(u.x >> 16));
                float gn = bf2f((short)(u.y & 0xffff));
                float er = __expf(-(gr + acc[hf * 3 + 0][reg]));
                float r = __builtin_amdgcn_rcpf(1.0f + er);
                float ez = __expf(-(gz + acc[hf * 3 + 1][reg]));
                float z = __builtin_amdgcn_rcpf(1.0f + ez);
                float xx = gn + r * acc[hf * 3 + 2][reg];
                float e2 = __expf(-2.0f * fabsf(xx));
                float nv = copysignf((1.0f - e2) * __builtin_amdgcn_rcpf(1.0f + e2), xx);
                float hnew = (1.0f - z) * nv + z * hprev[hf * 4 + reg];
                hprev[hf * 4 + reg] = hnew;
                __hip_bfloat16 qb = __float2bfloat16(hnew);
                int row = lg * 4 + reg;
                int slot = (w * 4 + hf * 2 + (lr >> 3)) ^ (row & 7);
                HB16[p2 * 4096 + row * 256 + slot * 8 + (lr & 7)] = *(short*)&qb;
            }
        if (t + 1 < T) {
            const __hip_bfloat16* gp =
                gip + ((size_t)((t + 1) * 2 + loc) * 8 + w) * 2048;
#pragma unroll
            for (int i = 0; i < 8; ++i)
                gv[i] = *(const uint2*)(gp + (i >> 2) * 1024 + (i & 3) * 256 + lane * 4);
        }
        bar_lgkm();
    }
    if (hTp) {
#pragma unroll
        for (int hf = 0; hf < 2; ++hf)
#pragma unroll
            for (int reg = 0; reg < 4; ++reg) {
                int row = lg * 4 + reg, col = w * 32 + hf * 16 + lr;
                hTp[(size_t)(mb + row) * H + col] = hprev[hf * 4 + reg];
            }
    }
}

// ---------------- merged = concat(tag_h, enc_h) @ proj_W^T + proj_b --------
__global__ void k_proj(const float* tag_h, const float* enc_h,
                       const float* W4p, const float* pb, float* merged) {
    __shared__ float c[2 * H];
    int b = blockIdx.x, tid = threadIdx.x;
    c[tid] = tag_h[b * H + tid];
    c[H + tid] = enc_h[b * H + tid];
    __syncthreads();
    float acc = 0.f;
#pragma unroll 4
    for (int k4 = 0; k4 < 128; ++k4) {
        float4 cv = *(const float4*)&c[k4 * 4];
        float4 wv = ((const float4*)(W4p + (size_t)k4 * 1024))[tid];
        acc += dot4(cv, wv);
    }
    merged[b * H + tid] = acc + pb[tid];
}

// ---------------- fused dec scan + logits GEMM -----------------------------
// blocks 0,1: dec scan (publishes prog[loc]); blocks 2+: logits (2 M-tiles).
__global__ __launch_bounds__(512) void k_declog(
    const __hip_bfloat16* gi_dec, const __hip_bfloat16* Wdec,
    const float* dec_bhh, const float* merged, __hip_bfloat16* decA,
    int* prog, const __hip_bfloat16* Bw, const float* bias, float* dout,
    float* pmax, float* psum) {
    __shared__ __align__(16) char smem[67584];
    int tid = threadIdx.x;
    int wave = tid >> 6, lane = tid & 63, lr = lane & 15, lg = lane >> 4;

    if (blockIdx.x < 2) {
        // ================= dec scan =================
        uint4* WL = (uint4*)smem;                  // [8][6][64]
        uint4* HBF = (uint4*)(smem + 49152);       // [2][512]
        short* HB16 = (short*)HBF;
        int loc = blockIdx.x, mb = loc * 16, w = wave;
        const int T = TTGT;

        short8 wreg[42];
        const uint4* Wg4 = (const uint4*)Wdec;
#pragma unroll
        for (int f = 0; f < 42; ++f) {
            uint4 v = Wg4[(size_t)(w * 48 + f) * 64 + lane];
            wreg[f] = *(short8*)&v;
        }
#pragma unroll
        for (int i = 0; i < 6; ++i)
            WL[(w * 6 + i) * 64 + lane] =
                Wg4[(size_t)(w * 48 + 42 + i) * 64 + lane];

        float bnv[2];
        bnv[0] = dec_bhh[512 + w * 32 + lr];
        bnv[1] = dec_bhh[512 + w * 32 + 16 + lr];

        float hprev[8];
#pragma unroll
        for (int hf = 0; hf < 2; ++hf)
#pragma unroll
            for (int reg = 0; reg < 4; ++reg) {
                int row = lg * 4 + reg, col = w * 32 + hf * 16 + lr;
                float hv = merged[(size_t)(mb + row) * H + col];
                hprev[hf * 4 + reg] = hv;
                __hip_bfloat16 q = __float2bfloat16(hv);
                int slot = (w * 4 + hf * 2 + (lr >> 3)) ^ (row & 7);
                HB16[row * 256 + slot * 8 + (lr & 7)] = *(short*)&q;
            }
        uint2 gv[8];
        {
            const __hip_bfloat16* gp = gi_dec + ((size_t)loc * 8 + w) * 2048;
#pragma unroll
            for (int i = 0; i < 8; ++i)
                gv[i] = *(const uint2*)(gp + (i >> 2) * 1024 + (i & 3) * 256 + lane * 4);
        }
        __syncthreads();

        const short8* HSbase = (const short8*)HBF;
        const short8* WLs = (const short8*)WL;
        for (int t = 0; t < T; ++t) {
            int p = t & 1, p2 = p ^ 1;
            const short8* HS = HSbase + p * 512;
            f32x4 acc[6];
            acc[0] = (f32x4){0.f, 0.f, 0.f, 0.f};
            acc[1] = acc[0];
            acc[2] = (f32x4){bnv[0], bnv[0], bnv[0], bnv[0]};
            acc[3] = acc[0];
            acc[4] = acc[0];
            acc[5] = (f32x4){bnv[1], bnv[1], bnv[1], bnv[1]};
#pragma unroll
            for (int ks = 0; ks < 7; ++ks) {
                short8 a = HS[lr * 32 + ((ks * 4 + lg) ^ (lr & 7))];
#pragma unroll
                for (int hf = 0; hf < 2; ++hf)
#pragma unroll
                    for (int q = 0; q < 3; ++q)
                        acc[hf * 3 + q] = __builtin_amdgcn_mfma_f32_16x16x32_bf16(
                            a, wreg[ks * 6 + hf * 3 + q], acc[hf * 3 + q], 0, 0, 0);
            }
            {
                short8 a = HS[lr * 32 + ((28 + lg) ^ (lr & 7))];
#pragma unroll
                for (int hf = 0; hf < 2; ++hf)
#pragma unroll
                    for (int q = 0; q < 3; ++q) {
                        short8 bv = WLs[(w * 6 + hf * 3 + q) * 64 + lane];
                        acc[hf * 3 + q] = __builtin_amdgcn_mfma_f32_16x16x32_bf16(
                            a, bv, acc[hf * 3 + q], 0, 0, 0);
                    }
            }
#pragma unroll
            for (int hf = 0; hf < 2; ++hf)
#pragma unroll
                for (int reg = 0; reg < 4; ++reg) {
                    uint2 u = gv[hf * 4 + reg];
                    float gr = bf2f((short)(u.x & 0xffff));
                    float gz = bf2f((short)(u.x >> 16));
                    float gn = bf2f((short)(u.y & 0xffff));
                    float er = __expf(-(gr + acc[hf * 3 + 0][reg]));
                    float r = __builtin_amdgcn_rcpf(1.0f + er);
                    float ez = __expf(-(gz + acc[hf * 3 + 1][reg]));
                    float z = __builtin_amdgcn_rcpf(1.0f + ez);
                    float xx = gn + r * acc[hf * 3 + 2][reg];
                    float e2 = __expf(-2.0f * fabsf(xx));
                    float nv = copysignf(
                        (1.0f - e2) * __builtin_amdgcn_rcpf(1.0f + e2), xx);
                    float hnew = (1.0f - z) * nv + z * hprev[hf * 4 + reg];
                    hprev[hf * 4 + reg] = hnew;
                    __hip_bfloat16 qb = __float2bfloat16(hnew);
                    int row = lg * 4 + reg;
                    int slot = (w * 4 + hf * 2 + (lr >> 3)) ^ (row & 7);
                    HB16[p2 * 4096 + row * 256 + slot * 8 + (lr & 7)] = *(short*)&qb;
                }
            // store output slice t-1 (h entering step t)
            if (t >= 1) {
                int lb = tid >> 5, ch = tid & 31;
                short8 hv = HSbase[p * 512 + lb * 32 + (ch ^ (lb & 7))];
                *(short8*)(decA + (size_t)((t - 1) * NBATCH + mb + lb) * H + ch * 8) = hv;
            }
            bool pub = ((t & 1) == 0) && t >= 2;
            if (pub) asm volatile("s_waitcnt vmcnt(0)" ::: "memory");
            if (t + 1 < T) {
                const __hip_bfloat16* gp =
                    gi_dec + ((size_t)((t + 1) * 2 + loc) * 8 + w) * 2048;
#pragma unroll
                for (int i = 0; i < 8; ++i)
                    gv[i] = *(const uint2*)(gp + (i >> 2) * 1024 + (i & 3) * 256 + lane * 4);
            }
            bar_lgkm();
            if (pub && tid == 0) {
                __threadfence();
                __hip_atomic_store(&prog[loc], t, __ATOMIC_RELEASE,
                                   __HIP_MEMORY_SCOPE_AGENT);
            }
        }
        // tail: slice T-1 (h after last step, from buffer T&1)
        {
            int lb = tid >> 5, ch = tid & 31;
            short8 hv = HSbase[(T & 1) * 512 + lb * 32 + (ch ^ (lb & 7))];
            *(short8*)(decA + (size_t)((T - 1) * NBATCH + mb + lb) * H + ch * 8) = hv;
        }
        asm volatile("s_waitcnt vmcnt(0)" ::: "memory");
        __syncthreads();
        if (tid == 0) {
            __threadfence();
            __hip_atomic_store(&prog[loc], TTGT, __ATOMIC_RELEASE,
                               __HIP_MEMORY_SCOPE_AGENT);
        }
        return;
    }

    // ================= logits =================
    uint4* bsm = (uint4*)smem;                 // 32KB B tile
    float* cst = (float*)(smem + 32768);       // [8][16][68]
    int lbid = blockIdx.x - 2;
    int mpair = lbid / NT, nblk = lbid % NT;
    int wg2 = wave >> 2, wsub = wave & 3;
    int mblk = mpair * 2 + wg2;
    int m0 = mblk * 64, n0 = nblk * 64;

    const uint4* Bg = (const uint4*)(Bw + (size_t)n0 * H);
#pragma unroll
    for (int i = 0; i < 4; ++i) {
        int c = tid + i * 512;
        int r = c >> 5, g = c & 31;
        bsm[(r << 5) | (g ^ (r & 7))] = Bg[c];
    }
    float biasv[4];
    bool valid[4];
#pragma unroll
    for (int ns = 0; ns < 4; ++ns) {
        int n = n0 + ns * 16 + lr;
        valid[ns] = (n < VSZ);
        biasv[ns] = valid[ns] ? bias[n] : 0.f;
    }
    // wait for dec timesteps [4*mpair, 4*mpair+3] (acquire also invalidates L1)
    if (tid == 0) {
        int need = 4 * mpair + 4;
        while (__hip_atomic_load(&prog[0], __ATOMIC_ACQUIRE,
                                 __HIP_MEMORY_SCOPE_AGENT) < need ||
               __hip_atomic_load(&prog[1], __ATOMIC_ACQUIRE,
                                 __HIP_MEMORY_SCOPE_AGENT) < need)
            __builtin_amdgcn_s_sleep(8);
    }
    __syncthreads();

    short8 areg[8];
    const uint4* Ar = (const uint4*)(decA + (size_t)(m0 + wsub * 16 + lr) * H);
#pragma unroll
    for (int ks = 0; ks < 8; ++ks) {
        uint4 v = Ar[ks * 4 + lg];
        areg[ks] = *(short8*)&v;
    }
    f32x4 acc[4];
#pragma unroll
    for (int ns = 0; ns < 4; ++ns) acc[ns] = (f32x4){0.f, 0.f, 0.f, 0.f};
    const short8* L = (const short8*)bsm;
#pragma unroll
    for (int ks = 0; ks < 8; ++ks) {
        int ga = ks * 4 + lg;
#pragma unroll
        for (int ns = 0; ns < 4; ++ns) {
            int rb = ns * 16 + lr;
            acc[ns] = __builtin_amdgcn_mfma_f32_16x16x32_bf16(
                areg[ks], L[(rb << 5) | (ga ^ (rb & 7))], acc[ns], 0, 0, 0);
        }
    }
    float* cw = cst + wave * (16 * 68);
#pragma unroll
    for (int reg = 0; reg < 4; ++reg) {
        int m = m0 + wsub * 16 + lg * 4 + reg;
        float v[4];
        float rm = -INFINITY;
#pragma unroll
        for (int ns = 0; ns < 4; ++ns) {
            v[ns] = acc[ns][reg] + biasv[ns];
            if (valid[ns]) rm = fmaxf(rm, v[ns]);
            cw[(lg * 4 + reg) * 68 + ns * 16 + lr] = v[ns];
        }
        for (int off = 1; off < 16; off <<= 1) rm = fmaxf(rm, __shfl_xor(rm, off));
        float se = 0.f;
#pragma unroll
        for (int ns = 0; ns < 4; ++ns)
            if (valid[ns]) se += __expf(v[ns] - rm);
        for (int off = 1; off < 16; off <<= 1) se += __shfl_xor(se, off);
        if (lr == 0) {
            pmax[(size_t)m * NT + nblk] = rm;
            psum[(size_t)m * NT + nblk] = se;
        }
    }
    float* dbase = dout + 2 + (size_t)(m0 + wsub * 16) * VSZ + n0;
    bool colok = (n0 + lane < VSZ);
#pragma unroll
    for (int rl = 0; rl < 16; ++rl) {
        float val = cw[rl * 68 + lane];
        if (colok) dbase[(size_t)rl * VSZ + lane] = val;
    }
}

// ---------------- per-row logsumexp from tile partials ---------------------
__global__ void k_lse(const float* pmax, const float* psum, float* lse) {
    int m = blockIdx.x, tid = threadIdx.x;
    __shared__ float sm[4];
    float lm = -INFINITY;
    for (int i = tid; i < NT; i += 256) lm = fmaxf(lm, pmax[(size_t)m * NT + i]);
    for (int off = 1; off < 64; off <<= 1) lm = fmaxf(lm, __shfl_xor(lm, off));
    if ((tid & 63) == 0) sm[tid >> 6] = lm;
    __syncthreads();
    float M = fmaxf(fmaxf(sm[0], sm[1]), fmaxf(sm[2], sm[3]));
    __syncthreads();
    float s = 0.f;
    for (int i = tid; i < NT; i += 256)
        s += psum[(size_t)m * NT + i] * __expf(pmax[(size_t)m * NT + i] - M);
    for (int off = 1; off < 64; off <<= 1) s += __shfl_xor(s, off);
    if ((tid & 63) == 0) sm[tid >> 6] = s;
    __syncthreads();
    if (tid == 0) lse[m] = M + logf(sm[0] + sm[1] + sm[2] + sm[3]);
}

// ---------------- final NLL loss -------------------------------------------
__global__ void k_loss(const float* lse, const int* tgt, float* dout) {
    int tid = threadIdx.x;
    __shared__ float sm[4];
    float s = 0.f;
    for (int m = tid; m < MT; m += 256) {
        int tg = tgt[m];
        s += lse[m] - dout[2 + (size_t)m * VSZ + tg];
    }
    for (int off = 1; off < 64; off <<= 1) s += __shfl_xor(s, off);
    if ((tid & 63) == 0) sm[tid >> 6] = s;
    __syncthreads();
    if (tid == 0) {
        float total = sm[0] + sm[1] + sm[2] + sm[3];
        dout[0] = total / 32.0f;    // sum over t of mean over batch
        dout[1] = total / 1280.0f;  // / T_tgt
    }
}

// ---------------------------------------------------------------------------
extern "C" void kernel_launch(void* const* d_in, const int* in_sizes, int n_in,
                              void* d_out, int out_size, void* d_ws,
                              size_t ws_size, hipStream_t stream) {
    const int* input_tensor = (const int*)d_in[0];
    const int* target_tensor = (const int*)d_in[1];
    const int* tag_tensor = (const int*)d_in[2];
    const float* enc_emb = (const float*)d_in[3];
    const float* enc_Wih = (const float*)d_in[4];
    const float* enc_Whh = (const float*)d_in[5];
    const float* enc_bih = (const float*)d_in[6];
    const float* enc_bhh = (const float*)d_in[7];
    const float* tag_emb = (const float*)d_in[8];
    const float* tag_Wih = (const float*)d_in[9];
    const float* tag_Whh = (const float*)d_in[10];
    const float* tag_bih = (const float*)d_in[11];
    const float* tag_bhh = (const float*)d_in[12];
    const float* proj_W = (const float*)d_in[13];
    const float* proj_b = (const float*)d_in[14];
    const float* dec_Wih = (const float*)d_in[15];
    const float* dec_Whh = (const float*)d_in[16];
    const float* dec_bih = (const float*)d_in[17];
    const float* dec_bhh = (const float*)d_in[18];
    const float* out_W = (const float*)d_in[19];
    const float* out_b = (const float*)d_in[20];

    char* wsb = (char*)d_ws;
    size_t o = 0;
    auto alloc = [&](size_t bytes) {
        size_t r = o;
        o += (bytes + 511) & ~(size_t)511;
        return r;
    };
    float* W4_enc_ih = (float*)(wsb + alloc(H3 * H * 4));
    float* W4_tag_ih = (float*)(wsb + alloc(H3 * H * 4));
    float* W4_dec_ih = (float*)(wsb + alloc(H3 * H * 4));
    float* W4_proj   = (float*)(wsb + alloc(H * 2 * H * 4));
    // gi buffers (bf16): [T][2][8][2048] shorts = T * 64KB
    __hip_bfloat16* gi_enc = (__hip_bfloat16*)(wsb + alloc((size_t)TIN * 65536));
    __hip_bfloat16* gi_tag = (__hip_bfloat16*)(wsb + alloc((size_t)TTAG * 65536));
    __hip_bfloat16* gi_dec = (__hip_bfloat16*)(wsb + alloc((size_t)TTGT * 65536));
    float* enc_h  = (float*)(wsb + alloc(NBATCH * H * 4));
    float* tag_h  = (float*)(wsb + alloc(NBATCH * H * 4));
    float* merged = (float*)(wsb + alloc(NBATCH * H * 4));
    float* lse    = (float*)(wsb + alloc(MT * 4));
    int*   prog   = (int*)(wsb + alloc(64 * 4));
    __hip_bfloat16* Wp_enc = (__hip_bfloat16*)(wsb + alloc(H3 * H * 2));
    __hip_bfloat16* Wp_tag = (__hip_bfloat16*)(wsb + alloc(H3 * H * 2));
    __hip_bfloat16* Wp_dec = (__hip_bfloat16*)(wsb + alloc(H3 * H * 2));
    __hip_bfloat16* outWb  = (__hip_bfloat16*)(wsb + alloc((size_t)VP * H * 2));
    __hip_bfloat16* decA   = (__hip_bfloat16*)(wsb + alloc((size_t)MT * H * 2));
    float* pmax = (float*)(wsb + alloc((size_t)MT * NT * 4));
    float* psum = (float*)(wsb + alloc((size_t)MT * NT * 4));

    float* dout = (float*)d_out;

    // 1) prep: Wih/proj transposes + Whh->fragment bf16 + zero prog
    k_prep<<<dim3(H3, 7), 256, 0, stream>>>(
        enc_Wih, tag_Wih, dec_Wih, proj_W, enc_Whh, tag_Whh, dec_Whh,
        W4_enc_ih, W4_tag_ih, W4_dec_ih, W4_proj, Wp_enc, Wp_tag, Wp_dec,
        prog);

    // 2) gi precompute (3 GRUs, per-lane bf16 layout) + out_W->bf16
    k_gi_cvt<<<NGI + NCVT, 256, 0, stream>>>(
        input_tensor, tag_tensor, target_tensor, enc_emb, tag_emb, W4_enc_ih,
        W4_tag_ih, W4_dec_ih, enc_bih, enc_bhh, tag_bih, tag_bhh, dec_bih,
        dec_bhh, gi_enc, gi_tag, gi_dec, out_W, outWb);

    // 3) encoder + tag GRU scans (4 independent blocks)
    k_scan<<<4, 512, 0, stream>>>(
        2, gi_enc, Wp_enc, enc_bhh, enc_h, TIN,
        gi_tag, Wp_tag, tag_bhh, tag_h, TTAG);

    // 4) proj -> merged
    k_proj<<<NBATCH, 256, 0, stream>>>(tag_h, enc_h, W4_proj, proj_b, merged);

    // 5) fused dec scan + logits GEMM (blocks 0,1 = scan; 2.. = logits)
    k_declog<<<2 + 10 * NT, 512, 0, stream>>>(
        gi_dec, Wp_dec, dec_bhh, merged, decA, prog, outWb, out_b, dout,
        pmax, psum);

    // 6) per-row logsumexp
    k_lse<<<MT, 256, 0, stream>>>(pmax, psum, lse);

    // 7) loss scalars
    k_loss<<<1, 256, 0, stream>>>(lse, target_tensor, dout);
}

// Round 11
// 447.970 us; speedup vs baseline: 1.3580x; 1.3580x over previous
//
#include <hip/hip_runtime.h>
#include <hip/hip_bf16.h>
#include <math.h>

// ---------------------------------------------------------------------------
// Seq2Seq: enc GRU (T=50) + tag GRU (T=20) -> proj -> dec GRU (T=40)
//          -> logits GEMM (1280x50003, K=256, bf16 MFMA) -> LSE -> NLL loss
//
// Round 11: revert r10 fusion (L2 thrash: FETCH 5MB->130MB).  Scan at
// 16 waves (1024 thr) = 4 waves/SIMD for 2x TLP:
//   wave w owns gate-cols w*16..w*16+15 of all 3 gates -> 3 acc chains,
//   24 MFMAs/step; 18 frags in regs (72 VGPR) + 6 in LDS -> fits 128 cap.
//   Layout is a re-indexing of r10's validated layout (w16 = 2*w8+hf).
// k_logits: nontemporal stores for the 290MB logit stream.
// ---------------------------------------------------------------------------

#define H 256
#define H3 768
#define NBATCH 32
#define TIN 50
#define TTGT 40
#define TTAG 20
#define VSZ 50003
#define VP 50048          // padded to 64
#define NT 782            // VP / 64
#define MT 1280           // TTGT * NBATCH
#define NGI 330           // 110 timesteps * 3 gates
#define NCVT 12512        // VP*H/4/256

typedef float f32x4 __attribute__((ext_vector_type(4)));
typedef short short8 __attribute__((ext_vector_type(8)));

__device__ __forceinline__ float dot4(float4 a, float4 b) {
    return a.x * b.x + a.y * b.y + a.z * b.z + a.w * b.w;
}

__device__ __forceinline__ float bf2f(short s) {
    unsigned int u = ((unsigned int)(unsigned short)s) << 16;
    return __builtin_bit_cast(float, u);
}

// barrier with LDS-only drain: leaves global loads in flight
__device__ __forceinline__ void bar_lgkm() {
    asm volatile("s_waitcnt lgkmcnt(0)" ::: "memory");
    __builtin_amdgcn_s_barrier();
    __builtin_amdgcn_sched_barrier(0);
}

// ---------------- prep: Wih/proj transpose + Whh -> MFMA-B fragments -------
// fragment order (16-wave): out[w16][f][lane][8], f = ks*3 + q,
//   row = q*256 + w16*16 + (lane&15), k = ks*32 + (lane>>4)*8
__global__ void k_prep(const float* eWih, const float* tWih, const float* dWih,
                       const float* projW, const float* eWhh, const float* tWhh,
                       const float* dWhh, float* d0, float* d1, float* d2,
                       float* d3, __hip_bfloat16* p0, __hip_bfloat16* p1,
                       __hip_bfloat16* p2) {
    int which = blockIdx.y;
    if (which < 4) {
        const float* s;
        float* d;
        int N, K;
        switch (which) {
            case 0: s = eWih; d = d0; N = H3; K = H; break;
            case 1: s = tWih; d = d1; N = H3; K = H; break;
            case 2: s = dWih; d = d2; N = H3; K = H; break;
            default: s = projW; d = d3; N = H; K = 2 * H; break;
        }
        int n = blockIdx.x;
        if (n >= N) return;
        for (int k = threadIdx.x; k < K; k += 256)
            d[(size_t)(k >> 2) * (N * 4) + n * 4 + (k & 3)] = s[(size_t)n * K + k];
    } else {
        if (blockIdx.x >= 96) return;
        const float* s = which == 4 ? eWhh : (which == 5 ? tWhh : dWhh);
        __hip_bfloat16* d = which == 4 ? p0 : (which == 5 ? p1 : p2);
        int idx = blockIdx.x * 256 + threadIdx.x;  // 0..24575
        int lane = idx & 63;
        int f = (idx >> 6) % 24;
        int w = idx / (24 * 64);
        int ks = f / 3, q = f % 3;
        int row = (q << 8) + (w << 4) + (lane & 15);
        int k = (ks << 5) + ((lane >> 4) << 3);
#pragma unroll
        for (int j = 0; j < 8; ++j)
            d[(size_t)idx * 8 + j] = __float2bfloat16(s[(size_t)row * H + k + j]);
    }
}

// ---------------- gi -> per-lane MFMA layout (bf16)  [+ outW cvt] ----------
// GIP[t][loc][w16][reg][lane][4] bf16 = {r,z,n,pad}; bih(+bhh r,z) folded.
__global__ __launch_bounds__(256) void k_gi_cvt(
    const int* in_toks, const int* tag_toks, const int* tgt_toks,
    const float* enc_emb, const float* tag_emb, const float* W4e,
    const float* W4t, const float* W4d, const float* bih_e, const float* bhh_e,
    const float* bih_t, const float* bhh_t, const float* bih_d,
    const float* bhh_d, __hip_bfloat16* gi_e, __hip_bfloat16* gi_t,
    __hip_bfloat16* gi_d, const float* outW, __hip_bfloat16* outWb) {
    int bx = blockIdx.x, tid = threadIdx.x;
    if (bx >= NGI) {
        int i4 = ((bx - NGI) * 256 + tid) * 4;
        if (i4 >= VP * H) return;
        int row = i4 >> 8;
        float4 v;
        if (row < VSZ) v = *(const float4*)(outW + i4);
        else v = make_float4(0.f, 0.f, 0.f, 0.f);
        outWb[i4 + 0] = __float2bfloat16(v.x);
        outWb[i4 + 1] = __float2bfloat16(v.y);
        outWb[i4 + 2] = __float2bfloat16(v.z);
        outWb[i4 + 3] = __float2bfloat16(v.w);
        return;
    }
    __shared__ float x[NBATCH][H];
    int g = bx % 3, tt = bx / 3;
    const int* toks;
    const float* emb;
    const float* W4;
    const float* bihp;
    const float* bhhp;
    __hip_bfloat16* gip;
    int t, mode;
    if (tt < TIN) {
        toks = in_toks; emb = enc_emb; W4 = W4e; bihp = bih_e; bhhp = bhh_e;
        gip = gi_e; t = tt; mode = 0;
    } else if (tt < TIN + TTAG) {
        toks = tag_toks; emb = tag_emb; W4 = W4t; bihp = bih_t; bhhp = bhh_t;
        gip = gi_t; t = tt - TIN; mode = 0;
    } else {
        toks = tgt_toks; emb = enc_emb; W4 = W4d; bihp = bih_d; bhhp = bhh_d;
        gip = gi_d; t = tt - TIN - TTAG; mode = 2;
    }
    for (int b = 0; b < NBATCH; ++b) {
        int tok;
        if (mode == 2) tok = (t == 0) ? 1 : toks[(t - 1) * NBATCH + b];
        else tok = toks[t * NBATCH + b];
        float v = emb[(size_t)tok * H + tid];
        if (mode == 2) v = fmaxf(v, 0.0f);
        x[b][tid] = v;
    }
    __syncthreads();
    int nb_ = tid & 63, mg = tid >> 6;
    float acc[4][8];
#pragma unroll
    for (int j = 0; j < 4; ++j)
#pragma unroll
        for (int mi = 0; mi < 8; ++mi) acc[j][mi] = 0.f;
    for (int k4 = 0; k4 < 64; ++k4) {
        const float4* wrow = (const float4*)(W4 + (size_t)k4 * 3072);
        float4 w0 = wrow[g * 256 + nb_];
        float4 w1 = wrow[g * 256 + nb_ + 64];
        float4 w2 = wrow[g * 256 + nb_ + 128];
        float4 w3 = wrow[g * 256 + nb_ + 192];
#pragma unroll
        for (int mi = 0; mi < 8; ++mi) {
            float4 xv = *(const float4*)&x[mg * 8 + mi][k4 * 4];
            acc[0][mi] += dot4(xv, w0);
            acc[1][mi] += dot4(xv, w1);
            acc[2][mi] += dot4(xv, w2);
            acc[3][mi] += dot4(xv, w3);
        }
    }
#pragma unroll
    for (int j = 0; j < 4; ++j) {
        int n = g * 256 + nb_ + j * 64;
        float bv = bihp[n] + (g < 2 ? bhhp[n] : 0.0f);
        int nn = n & 255;
        int ww = nn >> 4, lrr = nn & 15;   // w16, lane-row
#pragma unroll
        for (int mi = 0; mi < 8; ++mi) {
            int bm = mg * 8 + mi;
            int locb = bm >> 4, lmm = bm & 15;
            int lgg = lmm >> 2, reg = lmm & 3;
            size_t idx = ((size_t)(t * 2 + locb) * 16 + ww) * 1024 +
                         reg * 256 + (lgg * 16 + lrr) * 4 + g;
            gip[idx] = __float2bfloat16(acc[j][mi] + bv);
        }
    }
}

// ---------------- batch-split GRU scan, 16 waves (1024 thr) ----------------
// Block owns 16 batch rows.  Wave w owns gate-cols w*16..w*16+15 of all 3
// gates: 3 acc chains x 8 ks.  18 frags in regs, 6 (ks 6,7) in LDS.
__global__ __launch_bounds__(1024) void k_scan(
    int nset1,
    const __hip_bfloat16* gi1, const __hip_bfloat16* W1, const float* bhh1,
    const float* h01, float* hT1, __hip_bfloat16* out1, int T1,
    const __hip_bfloat16* gi2, const __hip_bfloat16* W2, const float* bhh2,
    const float* h02, float* hT2, __hip_bfloat16* out2, int T2) {
    __shared__ uint4 WL[16 * 6 * 64];  // 96KB: frags ks=6,7 for 16 waves
    __shared__ uint4 HBF[2][512];      // 16KB bf16 h dbuf

    int blk = blockIdx.x, tid = threadIdx.x;
    const __hip_bfloat16 *gip, *Wg;
    const float *bhh, *h0;
    float* hTp;
    __hip_bfloat16* outp;
    int T, loc;
    if (blk < nset1) {
        gip = gi1; Wg = W1; bhh = bhh1; h0 = h01; hTp = hT1; outp = out1;
        T = T1; loc = blk;
    } else {
        gip = gi2; Wg = W2; bhh = bhh2; h0 = h02; hTp = hT2; outp = out2;
        T = T2; loc = blk - nset1;
    }
    int mb = loc * 16;
    int w = tid >> 6, lane = tid & 63, lr = lane & 15, lg = lane >> 4;

    // wave's frags ks 0..5 -> 72 VGPRs
    short8 wreg[18];
    const uint4* Wg4 = (const uint4*)Wg;
#pragma unroll
    for (int f = 0; f < 18; ++f) {
        uint4 v = Wg4[(size_t)(w * 24 + f) * 64 + lane];
        wreg[f] = *(short8*)&v;
    }
    // frags ks 6,7 -> LDS
#pragma unroll
    for (int i = 0; i < 6; ++i)
        WL[(w * 6 + i) * 64 + lane] = Wg4[(size_t)(w * 24 + 18 + i) * 64 + lane];

    float bnv = bhh[512 + w * 16 + lr];

    // h master: 4 f32 regs (rows lg*4+reg, col w*16+lr)
    float hprev[4];
    short* HB16 = (short*)HBF;
#pragma unroll
    for (int reg = 0; reg < 4; ++reg) {
        int row = lg * 4 + reg, col = w * 16 + lr;
        float hv = h0 ? h0[(size_t)(mb + row) * H + col] : 0.0f;
        hprev[reg] = hv;
        __hip_bfloat16 q = __float2bfloat16(hv);
        int ch = w * 2 + (lr >> 3);
        int slot = ch ^ (row & 7);
        HB16[row * 256 + slot * 8 + (lr & 7)] = *(short*)&q;
    }
    // prefetch gi(0): 4 coalesced uint2 per thread
    uint2 gv[4];
    {
        const __hip_bfloat16* gp = gip + ((size_t)loc * 16 + w) * 1024;
#pragma unroll
        for (int reg = 0; reg < 4; ++reg)
            gv[reg] = *(const uint2*)(gp + reg * 256 + lane * 4);
    }
    __syncthreads();

    const short8* HSbase = (const short8*)HBF;
    const short8* WLs = (const short8*)WL;
    for (int t = 0; t < T; ++t) {
        int p = t & 1, p2 = p ^ 1;
        const short8* HS = HSbase + p * 512;
        // ---- MFMA: 3 acc chains (r,z,n), shared A fragment ----
        f32x4 acc[3];
        acc[0] = (f32x4){0.f, 0.f, 0.f, 0.f};
        acc[1] = acc[0];
        acc[2] = (f32x4){bnv, bnv, bnv, bnv};
#pragma unroll
        for (int ks = 0; ks < 6; ++ks) {
            short8 a = HS[lr * 32 + ((ks * 4 + lg) ^ (lr & 7))];
#pragma unroll
            for (int q = 0; q < 3; ++q)
                acc[q] = __builtin_amdgcn_mfma_f32_16x16x32_bf16(
                    a, wreg[ks * 3 + q], acc[q], 0, 0, 0);
        }
#pragma unroll
        for (int ks = 6; ks < 8; ++ks) {
            short8 a = HS[lr * 32 + ((ks * 4 + lg) ^ (lr & 7))];
#pragma unroll
            for (int q = 0; q < 3; ++q) {
                short8 bv = WLs[(w * 6 + (ks - 6) * 3 + q) * 64 + lane];
                acc[q] = __builtin_amdgcn_mfma_f32_16x16x32_bf16(
                    a, bv, acc[q], 0, 0, 0);
            }
        }
        // ---- pointwise: 4 h-elements per thread, MFMA register layout ----
#pragma unroll
        for (int reg = 0; reg < 4; ++reg) {
            uint2 u = gv[reg];
            float gr = bf2f((short)(u.x & 0xffff));
            float gz = bf2f((short)(u.x >> 16));
            float gn = bf2f((short)(u.y & 0xffff));
            float er = __expf(-(gr + acc[0][reg]));
            float r = __builtin_amdgcn_rcpf(1.0f + er);
            float ez = __expf(-(gz + acc[1][reg]));
            float z = __builtin_amdgcn_rcpf(1.0f + ez);
            float xx = gn + r * acc[2][reg];
            float e2 = __expf(-2.0f * fabsf(xx));
            float nv = copysignf((1.0f - e2) * __builtin_amdgcn_rcpf(1.0f + e2), xx);
            float hnew = (1.0f - z) * nv + z * hprev[reg];
            hprev[reg] = hnew;
            __hip_bfloat16 qb = __float2bfloat16(hnew);
            int row = lg * 4 + reg;
            int ch = w * 2 + (lr >> 3);
            int slot = ch ^ (row & 7);
            HB16[p2 * 4096 + row * 256 + slot * 8 + (lr & 7)] = *(short*)&qb;
        }
        // prefetch gi(t+1): hidden under next MFMA phase
        if (t + 1 < T) {
            const __hip_bfloat16* gp =
                gip + ((size_t)((t + 1) * 2 + loc) * 16 + w) * 1024;
#pragma unroll
            for (int reg = 0; reg < 4; ++reg)
                gv[reg] = *(const uint2*)(gp + reg * 256 + lane * 4);
        }
        // stream out h_t (= state entering step t) as outp slice t-1
        if (outp && t >= 1 && tid < 512) {
            int lb = tid >> 5, ch2 = tid & 31;
            short8 hv = HSbase[p * 512 + lb * 32 + (ch2 ^ (lb & 7))];
            *(short8*)(outp + (size_t)((t - 1) * NBATCH + mb + lb) * H + ch2 * 8) = hv;
        }
        bar_lgkm();
    }
    // tail: outp slice T-1; hT from f32 register master
    if (outp && tid < 512) {
        int lb = tid >> 5, ch2 = tid & 31;
        short8 hv = HSbase[(T & 1) * 512 + lb * 32 + (ch2 ^ (lb & 7))];
        *(short8*)(outp + (size_t)((T - 1) * NBATCH + mb + lb) * H + ch2 * 8) = hv;
    }
    if (hTp) {
#pragma unroll
        for (int reg = 0; reg < 4; ++reg) {
            int row = lg * 4 + reg, col = w * 16 + lr;
            hTp[(size_t)(mb + row) * H + col] = hprev[reg];
        }
    }
}

// ---------------- merged = concat(tag_h, enc_h) @ proj_W^T + proj_b --------
__global__ void k_proj(const float* tag_h, const float* enc_h,
                       const float* W4p, const float* pb, float* merged) {
    __shared__ float c[2 * H];
    int b = blockIdx.x, tid = threadIdx.x;
    c[tid] = tag_h[b * H + tid];
    c[H + tid] = enc_h[b * H + tid];
    __syncthreads();
    float acc = 0.f;
#pragma unroll 4
    for (int k4 = 0; k4 < 128; ++k4) {
        float4 cv = *(const float4*)&c[k4 * 4];
        float4 wv = ((const float4*)(W4p + (size_t)k4 * 1024))[tid];
        acc += dot4(cv, wv);
    }
    merged[b * H + tid] = acc + pb[tid];
}

// ---------------- logits GEMM: C[1280][50003] = A @ Bw^T + bias ------------
// A bf16 direct->regs; B in swizzled LDS; nontemporal logit stores.
__global__ __launch_bounds__(256) void k_logits(const __hip_bfloat16* A,
                                                const __hip_bfloat16* Bw,
                                                const float* bias, float* dout,
                                                float* pmax, float* psum) {
    __shared__ uint4 bsm[2048];       // 32KB B tile
    __shared__ float cst[4][16][68];  // 17KB per-wave C staging
    int bid = blockIdx.x;
    int wg = (bid & 7) * 1955 + (bid >> 3);  // XCD-aware bijective swizzle
    int nblk = wg / 20, mblk = wg % 20;      // N-major: 20 M-tiles per B-tile
    int m0 = mblk * 64, n0 = nblk * 64;
    int tid = threadIdx.x;
    int wave = tid >> 6, lane = tid & 63, lr = lane & 15, lg = lane >> 4;
    const uint4* Bg = (const uint4*)(Bw + (size_t)n0 * H);
#pragma unroll
    for (int i = 0; i < 8; ++i) {
        int c = tid + i * 256;
        int r = c >> 5, g = c & 31;
        bsm[(r << 5) | (g ^ (r & 7))] = Bg[c];
    }
    short8 areg[8];
    const uint4* Ar = (const uint4*)(A + (size_t)(m0 + wave * 16 + lr) * H);
#pragma unroll
    for (int ks = 0; ks < 8; ++ks) {
        uint4 v = Ar[ks * 4 + lg];
        areg[ks] = *(short8*)&v;
    }
    float biasv[4];
    bool valid[4];
#pragma unroll
    for (int ns = 0; ns < 4; ++ns) {
        int n = n0 + ns * 16 + lr;
        valid[ns] = (n < VSZ);
        biasv[ns] = valid[ns] ? bias[n] : 0.f;
    }
    __syncthreads();
    f32x4 acc[4];
#pragma unroll
    for (int ns = 0; ns < 4; ++ns) acc[ns] = (f32x4){0.f, 0.f, 0.f, 0.f};
    const short8* L = (const short8*)bsm;
#pragma unroll
    for (int ks = 0; ks < 8; ++ks) {
        int ga = ks * 4 + lg;
#pragma unroll
        for (int ns = 0; ns < 4; ++ns) {
            int rb = ns * 16 + lr;
            acc[ns] = __builtin_amdgcn_mfma_f32_16x16x32_bf16(
                areg[ks], L[(rb << 5) | (ga ^ (rb & 7))], acc[ns], 0, 0, 0);
        }
    }
    float* cw = &cst[wave][0][0];
#pragma unroll
    for (int reg = 0; reg < 4; ++reg) {
        int m = m0 + wave * 16 + lg * 4 + reg;
        float v[4];
        float rm = -INFINITY;
#pragma unroll
        for (int ns = 0; ns < 4; ++ns) {
            v[ns] = acc[ns][reg] + biasv[ns];
            if (valid[ns]) rm = fmaxf(rm, v[ns]);
            cw[(lg * 4 + reg) * 68 + ns * 16 + lr] = v[ns];
        }
        for (int off = 1; off < 16; off <<= 1) rm = fmaxf(rm, __shfl_xor(rm, off));
        float se = 0.f;
#pragma unroll
        for (int ns = 0; ns < 4; ++ns)
            if (valid[ns]) se += __expf(v[ns] - rm);
        for (int off = 1; off < 16; off <<= 1) se += __shfl_xor(se, off);
        if (lr == 0) {
            pmax[(size_t)m * NT + nblk] = rm;
            psum[(size_t)m * NT + nblk] = se;
        }
    }
    float* dbase = dout + 2 + (size_t)(m0 + wave * 16) * VSZ + n0;
    bool colok = (n0 + lane < VSZ);
#pragma unroll
    for (int rl = 0; rl < 16; ++rl) {
        float val = cst[wave][rl][lane];
        if (colok)
            __builtin_nontemporal_store(val, &dbase[(size_t)rl * VSZ + lane]);
    }
}

// ---------------- per-row logsumexp from tile partials ---------------------
__global__ void k_lse(const float* pmax, const float* psum, float* lse) {
    int m = blockIdx.x, tid = threadIdx.x;
    __shared__ float sm[4];
    float lm = -INFINITY;
    for (int i = tid; i < NT; i += 256) lm = fmaxf(lm, pmax[(size_t)m * NT + i]);
    for (int off = 1; off < 64; off <<= 1) lm = fmaxf(lm, __shfl_xor(lm, off));
    if ((tid & 63) == 0) sm[tid >> 6] = lm;
    __syncthreads();
    float M = fmaxf(fmaxf(sm[0], sm[1]), fmaxf(sm[2], sm[3]));
    __syncthreads();
    float s = 0.f;
    for (int i = tid; i < NT; i += 256)
        s += psum[(size_t)m * NT + i] * __expf(pmax[(size_t)m * NT + i] - M);
    for (int off = 1; off < 64; off <<= 1) s += __shfl_xor(s, off);
    if ((tid & 63) == 0) sm[tid >> 6] = s;
    __syncthreads();
    if (tid == 0) lse[m] = M + logf(sm[0] + sm[1] + sm[2] + sm[3]);
}

// ---------------- final NLL loss -------------------------------------------
__global__ void k_loss(const float* lse, const int* tgt, float* dout) {
    int tid = threadIdx.x;
    __shared__ float sm[4];
    float s = 0.f;
    for (int m = tid; m < MT; m += 256) {
        int tg = tgt[m];
        s += lse[m] - dout[2 + (size_t)m * VSZ + tg];
    }
    for (int off = 1; off < 64; off <<= 1) s += __shfl_xor(s, off);
    if ((tid & 63) == 0) sm[tid >> 6] = s;
    __syncthreads();
    if (tid == 0) {
        float total = sm[0] + sm[1] + sm[2] + sm[3];
        dout[0] = total / 32.0f;    // sum over t of mean over batch
        dout[1] = total / 1280.0f;  // / T_tgt
    }
}

// ---------------------------------------------------------------------------
extern "C" void kernel_launch(void* const* d_in, const int* in_sizes, int n_in,
                              void* d_out, int out_size, void* d_ws,
                              size_t ws_size, hipStream_t stream) {
    const int* input_tensor = (const int*)d_in[0];
    const int* target_tensor = (const int*)d_in[1];
    const int* tag_tensor = (const int*)d_in[2];
    const float* enc_emb = (const float*)d_in[3];
    const float* enc_Wih = (const float*)d_in[4];
    const float* enc_Whh = (const float*)d_in[5];
    const float* enc_bih = (const float*)d_in[6];
    const float* enc_bhh = (const float*)d_in[7];
    const float* tag_emb = (const float*)d_in[8];
    const float* tag_Wih = (const float*)d_in[9];
    const float* tag_Whh = (const float*)d_in[10];
    const float* tag_bih = (const float*)d_in[11];
    const float* tag_bhh = (const float*)d_in[12];
    const float* proj_W = (const float*)d_in[13];
    const float* proj_b = (const float*)d_in[14];
    const float* dec_Wih = (const float*)d_in[15];
    const float* dec_Whh = (const float*)d_in[16];
    const float* dec_bih = (const float*)d_in[17];
    const float* dec_bhh = (const float*)d_in[18];
    const float* out_W = (const float*)d_in[19];
    const float* out_b = (const float*)d_in[20];

    char* wsb = (char*)d_ws;
    size_t o = 0;
    auto alloc = [&](size_t bytes) {
        size_t r = o;
        o += (bytes + 511) & ~(size_t)511;
        return r;
    };
    float* W4_enc_ih = (float*)(wsb + alloc(H3 * H * 4));
    float* W4_tag_ih = (float*)(wsb + alloc(H3 * H * 4));
    float* W4_dec_ih = (float*)(wsb + alloc(H3 * H * 4));
    float* W4_proj   = (float*)(wsb + alloc(H * 2 * H * 4));
    // gi buffers (bf16): [T][2][16][1024] shorts = T * 64KB
    __hip_bfloat16* gi_enc = (__hip_bfloat16*)(wsb + alloc((size_t)TIN * 65536));
    __hip_bfloat16* gi_tag = (__hip_bfloat16*)(wsb + alloc((size_t)TTAG * 65536));
    __hip_bfloat16* gi_dec = (__hip_bfloat16*)(wsb + alloc((size_t)TTGT * 65536));
    float* enc_h  = (float*)(wsb + alloc(NBATCH * H * 4));
    float* tag_h  = (float*)(wsb + alloc(NBATCH * H * 4));
    float* merged = (float*)(wsb + alloc(NBATCH * H * 4));
    float* lse    = (float*)(wsb + alloc(MT * 4));
    __hip_bfloat16* Wp_enc = (__hip_bfloat16*)(wsb + alloc(H3 * H * 2));
    __hip_bfloat16* Wp_tag = (__hip_bfloat16*)(wsb + alloc(H3 * H * 2));
    __hip_bfloat16* Wp_dec = (__hip_bfloat16*)(wsb + alloc(H3 * H * 2));
    __hip_bfloat16* outWb  = (__hip_bfloat16*)(wsb + alloc((size_t)VP * H * 2));
    __hip_bfloat16* decA   = (__hip_bfloat16*)(wsb + alloc((size_t)MT * H * 2));
    float* pmax = (float*)(wsb + alloc((size_t)MT * NT * 4));
    float* psum = (float*)(wsb + alloc((size_t)MT * NT * 4));

    float* dout = (float*)d_out;

    // 1) prep: Wih/proj transposes + Whh->fragment bf16 (16-wave order)
    k_prep<<<dim3(H3, 7), 256, 0, stream>>>(
        enc_Wih, tag_Wih, dec_Wih, proj_W, enc_Whh, tag_Whh, dec_Whh,
        W4_enc_ih, W4_tag_ih, W4_dec_ih, W4_proj, Wp_enc, Wp_tag, Wp_dec);

    // 2) gi precompute (3 GRUs, per-lane bf16 layout) + out_W->bf16
    k_gi_cvt<<<NGI + NCVT, 256, 0, stream>>>(
        input_tensor, tag_tensor, target_tensor, enc_emb, tag_emb, W4_enc_ih,
        W4_tag_ih, W4_dec_ih, enc_bih, enc_bhh, tag_bih, tag_bhh, dec_bih,
        dec_bhh, gi_enc, gi_tag, gi_dec, out_W, outWb);

    // 3) encoder + tag GRU scans (4 blocks x 1024 thr)
    k_scan<<<4, 1024, 0, stream>>>(
        2, gi_enc, Wp_enc, enc_bhh, nullptr, enc_h, nullptr, TIN,
        gi_tag, Wp_tag, tag_bhh, nullptr, tag_h, nullptr, TTAG);

    // 4) proj -> merged
    k_proj<<<NBATCH, 256, 0, stream>>>(tag_h, enc_h, W4_proj, proj_b, merged);

    // 5) decoder GRU scan (2 blocks x 1024 thr, writes bf16 A matrix)
    k_scan<<<2, 1024, 0, stream>>>(
        2, gi_dec, Wp_dec, dec_bhh, merged, nullptr, decA, TTGT,
        nullptr, nullptr, nullptr, nullptr, nullptr, nullptr, 0);

    // 6) logits GEMM + LSE partials (grid = 782*20)
    k_logits<<<NT * 20, 256, 0, stream>>>(decA, outWb, out_b, dout, pmax, psum);

    // 7) per-row logsumexp
    k_lse<<<MT, 256, 0, stream>>>(pmax, psum, lse);

    // 8) loss scalars
    k_loss<<<1, 256, 0, stream>>>(lse, target_tensor, dout);
}